// Round 10
// baseline (77.909 us; speedup 1.0000x reference)
//
#include <hip/hip_runtime.h>

#define LOG2E 1.4426950408889634f
#define LN2F  0.6931471805599453f
#define RS5F  0.4472135954999579f  // 1/sqrt(5)

// single-instruction ds_swizzle (BitMode: src = ((lane & AND) | OR) ^ XOR, 32-lane groups)
template<int XOR, int OR, int AND>
__device__ __forceinline__ float swz(float v) {
    return __int_as_float(__builtin_amdgcn_ds_swizzle(
        __float_as_int(v), (XOR << 10) | (OR << 5) | AND));
}
#define SWZX(v, m) swz<(m), 0, 0x1F>(v)      // xor-butterfly (bits 0-3 stay in 16-group)
#define EXP2(x)  __builtin_amdgcn_exp2f(x)   // raw v_exp_f32
#define LOG2_(x) __builtin_amdgcn_logf(x)    // raw v_log_f32
#define RCP_(x)  __builtin_amdgcn_rcpf(x)    // raw v_rcp_f32

__device__ __forceinline__ float bperm(int byte_addr, float v) {
    return __int_as_float(__builtin_amdgcn_ds_bpermute(byte_addr, __float_as_int(v)));
}

// 4 items per WAVE (16-lane item groups, 16 items per 256-block) — R8 shape.
// Lane u = lane&15 holds state entry u (row=u>>2, col=u&3).
// Combo digits: c1 = u>>2, c2 = u&3; in-lane j in [0,8): c0A = j>>2, c3A = j&3;
// C-combo = all-digit complement. Exactness: per-row max shifted out at load;
// no mid-round renorms; single final renorm.
// Eval uses the exact min-identity: with f = log2(1-0.5*2^(-|t|)),
//   contribution_A = min(t-1, f), contribution_C = min(-1-t, f)
// (t-1 <= f iff t <= 0), replacing cmp+2*cndmask with 2*v_min.
// launch_bounds(256,8): force <=64 VGPR so all 8 waves/SIMD stay resident.
__global__ __launch_bounds__(256, 8) void mfnet_layer_kernel(
    const float* __restrict__ log_qi,   // (N,4,4)
    const float* __restrict__ G,        // (N,8,4)
    const float* __restrict__ sqrt_2rho,// (N,)
    const float* __restrict__ alpha_ptr,// (1,)
    float* __restrict__ out,            // (N,4,4)
    int N)
{
    const int tid  = threadIdx.x;
    const int wv   = tid >> 6;
    const int lane = tid & 63;
    const int grp  = (lane >> 4) & 3;    // item within wave
    const int u    = lane & 15;
    const int ib   = blockIdx.x * 16 + wv * 4;

    // G staging: 4 items x 32 floats, item stride 40 (bases at banks 0/8/16/24
    // -> conflict-free 16B group-broadcast reads). Wave-local, no __syncthreads.
    __shared__ __align__(16) float sG[4][160];
    {
        size_t gidx = (size_t)ib * 32 + (size_t)(lane * 2);
        size_t gmax = (size_t)N * 32 - 2;
        if (gidx > gmax) gidx = gmax;
        float2 gv = *(const float2*)(G + gidx);
        *(float2*)&sG[wv][grp * 40 + u * 2] = gv;
    }

    const int it0    = ib + grp;
    const bool valid = (it0 < N);
    const int item   = valid ? it0 : (N - 1);

    const float alpha = alpha_ptr[0];
    const float alm1  = 1.0f - alpha;

    const int col = u & 3;               // state col, also c2
    const int row = u >> 2;              // state row, also c1

    // symbols with LOG2E folded in (whole pipeline in log2 units)
    const float rv = sqrt_2rho[item] * (RS5F * LOG2E);
    const float s1 = rv * (float)(2 * row - 3);
    const float s2 = rv * (float)(2 * col - 3);

    // distributed state, log2 units; shift out each row's initial max
    float slqD = log_qi[(size_t)item * 16 + u] * LOG2E;
    {
        float m1 = fmaxf(slqD, SWZX(slqD, 1));
        float m  = fmaxf(m1, SWZX(m1, 2));
        slqD -= m;
    }

    // softmax of all rows at once (4-lane packs)
    auto softmax_all = [&](float s) {
        float e   = EXP2(s);
        float t   = e + SWZX(e, 1);
        float den = t + SWZX(t, 2);
        return e * RCP_(den);
    };
    float qD = softmax_all(slqD);

    // bpermute byte addresses (shifted-lane-bit patterns not expressible in BitMode)
    const int gb   = (lane & 0x30) << 2;             // group-base byte address
    const int aQ1A = gb + ((4 + row) << 2);          // q_row1[c1]
    const int aQ1C = gb + ((4 + (row ^ 3)) << 2);    // q_row1[c1^3]
    const int aR1  = gb + (col << 4);                // a lane whose c1 == col

    float q1A = bperm(aQ1A, qD), q1C = bperm(aQ1C, qD);
    float q2A  = swz<0, 8, 0x13>(qD);    // q_row2[c2]
    float q2C  = swz<3, 8, 0x13>(qD);    // q_row2[c2^3]
    float q3v0 = swz<0, 12, 0x10>(qD);   // q_row3[0..3] broadcast within group
    float q3v1 = swz<0, 13, 0x10>(qD);
    float q3v2 = swz<0, 14, 0x10>(qD);
    float q3v3 = swz<0, 15, 0x10>(qD);

    // ---- laplace-log-cdf accumulation (log2 units); pair trick C = -A ----
    float lpA[8] = {0,0,0,0,0,0,0,0};
    float lpC[8] = {0,0,0,0,0,0,0,0};
    const float* gw = &sG[wv][grp * 40];
#pragma unroll
    for (int r = 0; r < 8; ++r) {
        float4 g  = *(const float4*)(gw + r * 4);
        float b12 = fmaf(g.y, s1, g.z * s2);
        float m0  = g.x * rv;
        float m3  = g.w * rv;
        float t0  = fmaf(m0, -3.0f, b12);   // c0 = 0
        float t1  = b12 - m0;               // c0 = 1
#pragma unroll
        for (int j = 0; j < 8; ++j) {
            float tb = (j & 4) ? t1 : t0;
            float t  = fmaf(m3, (float)(2 * (j & 3) - 3), tb);   // x*LOG2E
            float e  = EXP2(-fabsf(t));
            float lg = LOG2_(fmaf(e, -0.5f, 1.0f));
            lpA[j] += fminf(t - 1.0f, lg);      // exact: t-1 <= lg iff t <= 0
            lpC[j] += fminf(-1.0f - t, lg);
        }
    }

    // U-sums over c3 with q3 weights (C combo: c0C = 3-(j>>2), c3C = 3-(j&3))
    float UA0 = lpA[0]*q3v0 + lpA[1]*q3v1 + lpA[2]*q3v2 + lpA[3]*q3v3;
    float UA1 = lpA[4]*q3v0 + lpA[5]*q3v1 + lpA[6]*q3v2 + lpA[7]*q3v3;
    float UC3 = lpC[0]*q3v3 + lpC[1]*q3v2 + lpC[2]*q3v1 + lpC[3]*q3v0;
    float UC2 = lpC[4]*q3v3 + lpC[5]*q3v2 + lpC[6]*q3v1 + lpC[7]*q3v0;

    // ======== round 0 (groups = c0, in-lane) ========
    float JA, JC, q0v0, q0v1, q0v2, q0v3;
    {
        float preQ  = q1A * q2A;
        float preQC = q1C * q2C;
        float VA0 = UA0 * preQ,  VA1 = UA1 * preQ;    // -> ex cols 0,1
        float VC2 = UC2 * preQC, VC3 = UC3 * preQC;   // -> ex cols 2,3
        // reduce-scatter: pre-swap by bit0, then butterfly bits 1-3
        bool bb = (u & 1);
        float S01 = (bb ? VA1 : VA0) + SWZX(bb ? VA0 : VA1, 1);
        float S23 = (bb ? VC3 : VC2) + SWZX(bb ? VC2 : VC3, 1);
        S01 += SWZX(S01, 2); S01 += SWZX(S01, 4); S01 += SWZX(S01, 8);
        S23 += SWZX(S23, 2); S23 += SWZX(S23, 4); S23 += SWZX(S23, 8);
        float exD = (col & 2) ? S23 : S01;
        float bl = fmaf(alm1, slqD, alpha * exD);
        slqD = (row == 0) ? bl : slqD;
        qD = softmax_all(slqD);
        q0v0 = swz<0, 0, 0x10>(qD);
        q0v1 = swz<0, 1, 0x10>(qD);
        q0v2 = swz<0, 2, 0x10>(qD);
        q0v3 = swz<0, 3, 0x10>(qD);
        JA = q0v0*UA0 + q0v1*UA1;            // reusable rounds 1-2
        JC = q0v3*UC3 + q0v2*UC2;
    }

    // ======== round 1 (groups = c1 = bits 2-3) ========
    {
        float SA = q2A * JA, SC = q2C * JC;
        SA += SWZX(SA, 1); SA += SWZX(SA, 2);       // sum over c2
        SC += SWZX(SC, 1); SC += SWZX(SC, 2);
        float T = SA + SWZX(SC, 12);                // C of group c1^3 -> c1
        float exD = bperm(aR1, T);                  // ex[col]
        float bl = fmaf(alm1, slqD, alpha * exD);
        slqD = (row == 1) ? bl : slqD;
        qD = softmax_all(slqD);
        q1A = bperm(aQ1A, qD); q1C = bperm(aQ1C, qD);
    }

    // ======== round 2 (groups = c2 = bits 0-1) ========
    {
        float SA = q1A * JA, SC = q1C * JC;
        SA += SWZX(SA, 4); SA += SWZX(SA, 8);       // sum over c1
        SC += SWZX(SC, 4); SC += SWZX(SC, 8);
        float exD = SA + SWZX(SC, 3);               // lands on own lane: c2 == col
        float bl = fmaf(alm1, slqD, alpha * exD);
        slqD = (row == 2) ? bl : slqD;
        qD = softmax_all(slqD);
        q2A = swz<0, 8, 0x13>(qD);
        q2C = swz<3, 8, 0x13>(qD);
    }

    // ======== round 3 (groups = c3, in-lane; recompute from lp + q0v) ========
    {
        float WA = q1A * q2A, WC = q1C * q2C;
        float wa0 = WA * q0v0, wa1 = WA * q0v1;
        float wc3 = WC * q0v3, wc2 = WC * q0v2;
        float V0 = lpA[0]*wa0 + lpA[4]*wa1 + lpC[3]*wc3 + lpC[7]*wc2;
        float V1 = lpA[1]*wa0 + lpA[5]*wa1 + lpC[2]*wc3 + lpC[6]*wc2;
        float V2 = lpA[2]*wa0 + lpA[6]*wa1 + lpC[1]*wc3 + lpC[5]*wc2;
        float V3 = lpA[3]*wa0 + lpA[7]*wa1 + lpC[0]*wc3 + lpC[4]*wc2;
        bool bb = (u & 1);
        float S01 = (bb ? V1 : V0) + SWZX(bb ? V0 : V1, 1);
        float S23 = (bb ? V3 : V2) + SWZX(bb ? V2 : V3, 1);
        S01 += SWZX(S01, 2); S01 += SWZX(S01, 4); S01 += SWZX(S01, 8);
        S23 += SWZX(S23, 2); S23 += SWZX(S23, 4); S23 += SWZX(S23, 8);
        float exD = (col & 2) ? S23 : S01;
        float bl = fmaf(alm1, slqD, alpha * exD);
        slqD = (row == 3) ? bl : slqD;
    }

    // ---- single final renorm (all rows), then coalesced store ----
    {
        float m1 = fmaxf(slqD, SWZX(slqD, 1));
        float m  = fmaxf(m1, SWZX(m1, 2));
        slqD -= m;
    }
    if (valid) {
        out[(size_t)item * 16 + u] = slqD * LN2F;
    }
}

extern "C" void kernel_launch(void* const* d_in, const int* in_sizes, int n_in,
                              void* d_out, int out_size, void* d_ws, size_t ws_size,
                              hipStream_t stream) {
    const float* log_qi = (const float*)d_in[0];
    const float* G      = (const float*)d_in[1];
    const float* rho    = (const float*)d_in[2];
    // d_in[3] = n_var — unused by the reference
    const float* alpha  = (const float*)d_in[4];
    float* out = (float*)d_out;

    const int N = in_sizes[2];                 // 32768 batch items
    const int blocks = (N + 15) / 16;          // 16 items per block (4 per wave)
    mfnet_layer_kernel<<<blocks, 256, 0, stream>>>(log_qi, G, rho, alpha, out, N);
}

// Round 11
// 77.694 us; speedup vs baseline: 1.0028x; 1.0028x over previous
//
#include <hip/hip_runtime.h>

#define LOG2E 1.4426950408889634f
#define LN2F  0.6931471805599453f
#define RS5F  0.4472135954999579f  // 1/sqrt(5)

// log2(1 - e/2) = -(C1*e + C2*e^2 + C3*e^3 + C4*e^4), e in (0,1].
// C1..C3 = Taylor (log2e/(k*2^k)); C4 tuned so P(1) = 1 exactly (lg(1) = -1,
// keeps the min-identity exact at t=0). Max error ~2e-3 log2 units.
#define PC1 0.72134751f
#define PC2 0.18033688f
#define PC3 0.06011229f
#define PC4 0.03820332f

// single-instruction ds_swizzle (BitMode: src = ((lane & AND) | OR) ^ XOR, 32-lane groups)
template<int XOR, int OR, int AND>
__device__ __forceinline__ float swz(float v) {
    return __int_as_float(__builtin_amdgcn_ds_swizzle(
        __float_as_int(v), (XOR << 10) | (OR << 5) | AND));
}
#define SWZX(v, m) swz<(m), 0, 0x1F>(v)      // xor-butterfly (bits 0-3 stay in 16-group)
#define EXP2(x)  __builtin_amdgcn_exp2f(x)   // raw v_exp_f32
#define RCP_(x)  __builtin_amdgcn_rcpf(x)    // raw v_rcp_f32

__device__ __forceinline__ float bperm(int byte_addr, float v) {
    return __int_as_float(__builtin_amdgcn_ds_bpermute(byte_addr, __float_as_int(v)));
}

// 4 items per WAVE (16-lane item groups, 16 items per 256-block) — R8 shape.
// Lane u = lane&15 holds state entry u (row=u>>2, col=u&3).
// Combo digits: c1 = u>>2, c2 = u&3; in-lane j in [0,8): c0A = j>>2, c3A = j&3;
// C-combo = all-digit complement. Exactness: per-row max shifted out at load;
// no mid-round renorms; single final renorm.
// Eval: min-identity (t-1 <= lg iff t <= 0) + POLYNOMIAL lg (no v_log at all):
//   lg = -e*(PC1 + e*(PC2 + e*(PC3 + e*PC4))), e = 2^(-|t|)
// contribution_A = min(t-1, lg); contribution_C = min(-1-t, lg).
__global__ __launch_bounds__(256, 7) void mfnet_layer_kernel(
    const float* __restrict__ log_qi,   // (N,4,4)
    const float* __restrict__ G,        // (N,8,4)
    const float* __restrict__ sqrt_2rho,// (N,)
    const float* __restrict__ alpha_ptr,// (1,)
    float* __restrict__ out,            // (N,4,4)
    int N)
{
    const int tid  = threadIdx.x;
    const int wv   = tid >> 6;
    const int lane = tid & 63;
    const int grp  = (lane >> 4) & 3;    // item within wave
    const int u    = lane & 15;
    const int ib   = blockIdx.x * 16 + wv * 4;

    // G staging: 4 items x 32 floats, item stride 40 (bases at banks 0/8/16/24
    // -> conflict-free 16B group-broadcast reads). Wave-local, no __syncthreads.
    __shared__ __align__(16) float sG[4][160];
    {
        size_t gidx = (size_t)ib * 32 + (size_t)(lane * 2);
        size_t gmax = (size_t)N * 32 - 2;
        if (gidx > gmax) gidx = gmax;
        float2 gv = *(const float2*)(G + gidx);
        *(float2*)&sG[wv][grp * 40 + u * 2] = gv;
    }

    const int it0    = ib + grp;
    const bool valid = (it0 < N);
    const int item   = valid ? it0 : (N - 1);

    const float alpha = alpha_ptr[0];
    const float alm1  = 1.0f - alpha;

    const int col = u & 3;               // state col, also c2
    const int row = u >> 2;              // state row, also c1

    // symbols with LOG2E folded in (whole pipeline in log2 units)
    const float rv = sqrt_2rho[item] * (RS5F * LOG2E);
    const float s1 = rv * (float)(2 * row - 3);
    const float s2 = rv * (float)(2 * col - 3);

    // distributed state, log2 units; shift out each row's initial max
    float slqD = log_qi[(size_t)item * 16 + u] * LOG2E;
    {
        float m1 = fmaxf(slqD, SWZX(slqD, 1));
        float m  = fmaxf(m1, SWZX(m1, 2));
        slqD -= m;
    }

    // softmax of all rows at once (4-lane packs)
    auto softmax_all = [&](float s) {
        float e   = EXP2(s);
        float t   = e + SWZX(e, 1);
        float den = t + SWZX(t, 2);
        return e * RCP_(den);
    };
    float qD = softmax_all(slqD);

    // bpermute byte addresses (shifted-lane-bit patterns not expressible in BitMode)
    const int gb   = (lane & 0x30) << 2;             // group-base byte address
    const int aQ1A = gb + ((4 + row) << 2);          // q_row1[c1]
    const int aQ1C = gb + ((4 + (row ^ 3)) << 2);    // q_row1[c1^3]
    const int aR1  = gb + (col << 4);                // a lane whose c1 == col

    float q1A = bperm(aQ1A, qD), q1C = bperm(aQ1C, qD);
    float q2A  = swz<0, 8, 0x13>(qD);    // q_row2[c2]
    float q2C  = swz<3, 8, 0x13>(qD);    // q_row2[c2^3]
    float q3v0 = swz<0, 12, 0x10>(qD);   // q_row3[0..3] broadcast within group
    float q3v1 = swz<0, 13, 0x10>(qD);
    float q3v2 = swz<0, 14, 0x10>(qD);
    float q3v3 = swz<0, 15, 0x10>(qD);

    // ---- laplace-log-cdf accumulation (log2 units); pair trick C = -A ----
    float lpA[8] = {0,0,0,0,0,0,0,0};
    float lpC[8] = {0,0,0,0,0,0,0,0};
    const float* gw = &sG[wv][grp * 40];
#pragma unroll
    for (int r = 0; r < 8; ++r) {
        float4 g  = *(const float4*)(gw + r * 4);
        float b12 = fmaf(g.y, s1, g.z * s2);
        float m0  = g.x * rv;
        float m3  = g.w * rv;
        float t0  = fmaf(m0, -3.0f, b12);   // c0 = 0
        float t1  = b12 - m0;               // c0 = 1
#pragma unroll
        for (int j = 0; j < 8; ++j) {
            float tb = (j & 4) ? t1 : t0;
            float t  = fmaf(m3, (float)(2 * (j & 3) - 3), tb);   // x*LOG2E
            float e  = EXP2(-fabsf(t));
            float p  = fmaf(e, PC4, PC3);
            p = fmaf(e, p, PC2);
            p = fmaf(e, p, PC1);
            float ep = e * p;                   // = -lg
            lpA[j] += fminf(t - 1.0f, -ep);     // exact: t-1 <= lg iff t <= 0
            lpC[j] += fminf(-1.0f - t, -ep);
        }
    }

    // U-sums over c3 with q3 weights (C combo: c0C = 3-(j>>2), c3C = 3-(j&3))
    float UA0 = lpA[0]*q3v0 + lpA[1]*q3v1 + lpA[2]*q3v2 + lpA[3]*q3v3;
    float UA1 = lpA[4]*q3v0 + lpA[5]*q3v1 + lpA[6]*q3v2 + lpA[7]*q3v3;
    float UC3 = lpC[0]*q3v3 + lpC[1]*q3v2 + lpC[2]*q3v1 + lpC[3]*q3v0;
    float UC2 = lpC[4]*q3v3 + lpC[5]*q3v2 + lpC[6]*q3v1 + lpC[7]*q3v0;

    // ======== round 0 (groups = c0, in-lane) ========
    float JA, JC, q0v0, q0v1, q0v2, q0v3;
    {
        float preQ  = q1A * q2A;
        float preQC = q1C * q2C;
        float VA0 = UA0 * preQ,  VA1 = UA1 * preQ;    // -> ex cols 0,1
        float VC2 = UC2 * preQC, VC3 = UC3 * preQC;   // -> ex cols 2,3
        // reduce-scatter: pre-swap by bit0, then butterfly bits 1-3
        bool bb = (u & 1);
        float S01 = (bb ? VA1 : VA0) + SWZX(bb ? VA0 : VA1, 1);
        float S23 = (bb ? VC3 : VC2) + SWZX(bb ? VC2 : VC3, 1);
        S01 += SWZX(S01, 2); S01 += SWZX(S01, 4); S01 += SWZX(S01, 8);
        S23 += SWZX(S23, 2); S23 += SWZX(S23, 4); S23 += SWZX(S23, 8);
        float exD = (col & 2) ? S23 : S01;
        float bl = fmaf(alm1, slqD, alpha * exD);
        slqD = (row == 0) ? bl : slqD;
        qD = softmax_all(slqD);
        q0v0 = swz<0, 0, 0x10>(qD);
        q0v1 = swz<0, 1, 0x10>(qD);
        q0v2 = swz<0, 2, 0x10>(qD);
        q0v3 = swz<0, 3, 0x10>(qD);
        JA = q0v0*UA0 + q0v1*UA1;            // reusable rounds 1-2
        JC = q0v3*UC3 + q0v2*UC2;
    }

    // ======== round 1 (groups = c1 = bits 2-3) ========
    {
        float SA = q2A * JA, SC = q2C * JC;
        SA += SWZX(SA, 1); SA += SWZX(SA, 2);       // sum over c2
        SC += SWZX(SC, 1); SC += SWZX(SC, 2);
        float T = SA + SWZX(SC, 12);                // C of group c1^3 -> c1
        float exD = bperm(aR1, T);                  // ex[col]
        float bl = fmaf(alm1, slqD, alpha * exD);
        slqD = (row == 1) ? bl : slqD;
        qD = softmax_all(slqD);
        q1A = bperm(aQ1A, qD); q1C = bperm(aQ1C, qD);
    }

    // ======== round 2 (groups = c2 = bits 0-1) ========
    {
        float SA = q1A * JA, SC = q1C * JC;
        SA += SWZX(SA, 4); SA += SWZX(SA, 8);       // sum over c1
        SC += SWZX(SC, 4); SC += SWZX(SC, 8);
        float exD = SA + SWZX(SC, 3);               // lands on own lane: c2 == col
        float bl = fmaf(alm1, slqD, alpha * exD);
        slqD = (row == 2) ? bl : slqD;
        qD = softmax_all(slqD);
        q2A = swz<0, 8, 0x13>(qD);
        q2C = swz<3, 8, 0x13>(qD);
    }

    // ======== round 3 (groups = c3, in-lane; recompute from lp + q0v) ========
    {
        float WA = q1A * q2A, WC = q1C * q2C;
        float wa0 = WA * q0v0, wa1 = WA * q0v1;
        float wc3 = WC * q0v3, wc2 = WC * q0v2;
        float V0 = lpA[0]*wa0 + lpA[4]*wa1 + lpC[3]*wc3 + lpC[7]*wc2;
        float V1 = lpA[1]*wa0 + lpA[5]*wa1 + lpC[2]*wc3 + lpC[6]*wc2;
        float V2 = lpA[2]*wa0 + lpA[6]*wa1 + lpC[1]*wc3 + lpC[5]*wc2;
        float V3 = lpA[3]*wa0 + lpA[7]*wa1 + lpC[0]*wc3 + lpC[4]*wc2;
        bool bb = (u & 1);
        float S01 = (bb ? V1 : V0) + SWZX(bb ? V0 : V1, 1);
        float S23 = (bb ? V3 : V2) + SWZX(bb ? V2 : V3, 1);
        S01 += SWZX(S01, 2); S01 += SWZX(S01, 4); S01 += SWZX(S01, 8);
        S23 += SWZX(S23, 2); S23 += SWZX(S23, 4); S23 += SWZX(S23, 8);
        float exD = (col & 2) ? S23 : S01;
        float bl = fmaf(alm1, slqD, alpha * exD);
        slqD = (row == 3) ? bl : slqD;
    }

    // ---- single final renorm (all rows), then coalesced store ----
    {
        float m1 = fmaxf(slqD, SWZX(slqD, 1));
        float m  = fmaxf(m1, SWZX(m1, 2));
        slqD -= m;
    }
    if (valid) {
        out[(size_t)item * 16 + u] = slqD * LN2F;
    }
}

extern "C" void kernel_launch(void* const* d_in, const int* in_sizes, int n_in,
                              void* d_out, int out_size, void* d_ws, size_t ws_size,
                              hipStream_t stream) {
    const float* log_qi = (const float*)d_in[0];
    const float* G      = (const float*)d_in[1];
    const float* rho    = (const float*)d_in[2];
    // d_in[3] = n_var — unused by the reference
    const float* alpha  = (const float*)d_in[4];
    float* out = (float*)d_out;

    const int N = in_sizes[2];                 // 32768 batch items
    const int blocks = (N + 15) / 16;          // 16 items per block (4 per wave)
    mfnet_layer_kernel<<<blocks, 256, 0, stream>>>(log_qi, G, rho, alpha, out, N);
}